// Round 1
// baseline (2129.089 us; speedup 1.0000x reference)
//
#include <hip/hip_runtime.h>

#define D_MODEL 2048
#define NHEADS  16
#define DK      128
#define BATCH   2
#define SEQ     2048
#define MTOT    (BATCH*SEQ)   // 4096 rows

typedef unsigned short u16;
typedef unsigned int   u32;
typedef __bf16 bf16x8 __attribute__((ext_vector_type(8)));
typedef float  f32x4  __attribute__((ext_vector_type(4)));

__device__ __forceinline__ float b2f(u16 u) {
  return __uint_as_float(((u32)u) << 16);
}
__device__ __forceinline__ u16 f2b(float f) {  // RNE fp32 -> bf16
  u32 x = __float_as_uint(f);
  x += 0x7fffu + ((x >> 16) & 1u);
  return (u16)(x >> 16);
}

// ---------------- fp32 -> bf16 bulk convert ----------------
__global__ __launch_bounds__(256) void cvt_k(const float* __restrict__ in,
                                             u16* __restrict__ out, int n4) {
  int i = blockIdx.x * 256 + threadIdx.x;
  if (i >= n4) return;
  float4 v = ((const float4*)in)[i];
  u32 lo = (u32)f2b(v.x) | ((u32)f2b(v.y) << 16);
  u32 hi = (u32)f2b(v.z) | ((u32)f2b(v.w) << 16);
  ((uint2*)out)[i] = make_uint2(lo, hi);
}

// ---------------- RoPE (in-place on bf16 (B,H,S,DK)) ----------------
__global__ __launch_bounds__(256) void rope_k(u16* __restrict__ T) {
  int idx = blockIdx.x * 256 + threadIdx.x;   // one thread per (bh,s,pair)
  int p = idx & 63;                 // pair index 0..63
  int s = (idx >> 6) & (SEQ - 1);   // position
  // freq = 10000^(-p/64) = 2^(-p * log2(10000)/64)
  float freq = exp2f(-0.20762050593045951f * (float)p);
  float ang = (float)s * freq;
  float sn, cs;
  sincosf(ang, &sn, &cs);
  u32 v = *(u32*)(T + (size_t)idx * 2);
  float te = b2f((u16)(v & 0xffffu));
  float to = b2f((u16)(v >> 16));
  float e  = te * cs - to * sn;
  float od = te * sn + to * cs;
  u32 r = (u32)f2b(e) | ((u32)f2b(od) << 16);
  *(u32*)(T + (size_t)idx * 2) = r;
}

// ---------------- GEMM: Y(M,N) = A(M,K) @ B(N,K)^T, bf16 MFMA ----------------
// mode 0: outf[row*N+col] = acc + bias[col]           (fp32, final O-proj)
// mode 1: outb in (B, H, S, DK) layout, bf16          (Q/K/V projections)
__global__ __launch_bounds__(256) void gemm_bt(const u16* __restrict__ A,
                                               const u16* __restrict__ B,
                                               const int M, const int N, const int K,
                                               u16* __restrict__ outb,
                                               float* __restrict__ outf,
                                               const float* __restrict__ bias,
                                               const int mode) {
  constexpr int LDT = 40;  // padded row stride (shorts): 80B, 16B-aligned, derails pow2 banks
  __shared__ __align__(16) u16 As[128 * LDT];
  __shared__ __align__(16) u16 Bs[128 * LDT];

  const int t    = threadIdx.x;
  const int lane = t & 63;
  const int wave = t >> 6;
  const int wm   = wave >> 1, wn = wave & 1;       // 2x2 waves of 64x64
  const int quad = lane >> 4, l16 = lane & 15;
  const int m0 = blockIdx.y * 128, n0 = blockIdx.x * 128;
  const int cg = t & 3, r = t >> 2;                // staging: 16B col-group, row

  f32x4 acc[4][4] = {};

  const u16* Ap = A + (size_t)(m0 + r) * K + cg * 8;
  const u16* Bp = B + (size_t)(n0 + r) * K + cg * 8;
  const size_t rowJump = (size_t)64 * K;

  for (int k0 = 0; k0 < K; k0 += 32) {
    uint4 av0 = *(const uint4*)(Ap + k0);
    uint4 av1 = *(const uint4*)(Ap + k0 + rowJump);
    uint4 bv0 = *(const uint4*)(Bp + k0);
    uint4 bv1 = *(const uint4*)(Bp + k0 + rowJump);
    __syncthreads();
    *(uint4*)&As[(r)      * LDT + cg * 8] = av0;
    *(uint4*)&As[(r + 64) * LDT + cg * 8] = av1;
    *(uint4*)&Bs[(r)      * LDT + cg * 8] = bv0;
    *(uint4*)&Bs[(r + 64) * LDT + cg * 8] = bv1;
    __syncthreads();

    bf16x8 af[4], bfr[4];
#pragma unroll
    for (int i = 0; i < 4; ++i)
      af[i] = *(const bf16x8*)&As[(wm * 64 + i * 16 + l16) * LDT + quad * 8];
#pragma unroll
    for (int j = 0; j < 4; ++j)
      bfr[j] = *(const bf16x8*)&Bs[(wn * 64 + j * 16 + l16) * LDT + quad * 8];
#pragma unroll
    for (int i = 0; i < 4; ++i)
#pragma unroll
      for (int j = 0; j < 4; ++j)
        acc[i][j] = __builtin_amdgcn_mfma_f32_16x16x32_bf16(af[i], bfr[j], acc[i][j], 0, 0, 0);
  }

#pragma unroll
  for (int i = 0; i < 4; ++i) {
#pragma unroll
    for (int j = 0; j < 4; ++j) {
#pragma unroll
      for (int rr = 0; rr < 4; ++rr) {
        int row = m0 + wm * 64 + i * 16 + quad * 4 + rr;
        int col = n0 + wn * 64 + j * 16 + l16;
        float v = acc[i][j][rr];
        if (mode == 0) {
          outf[(size_t)row * N + col] = v + bias[col];
        } else {
          int b = row >> 11;            // row / SEQ  (M = BATCH*SEQ)
          int s = row & (SEQ - 1);
          int h = col >> 7;             // col / DK
          int d = col & (DK - 1);
          outb[(((size_t)(b * NHEADS + h)) * SEQ + s) * DK + d] = f2b(v);
        }
      }
    }
  }
}

// ---------------- Flash attention (fp32 vector), causal ----------------
// Q,K,V: bf16 (B,H,S,DK). out: bf16 (B,S,H*DK) rows for the O-proj GEMM.
__global__ __launch_bounds__(256) void attn_k(const u16* __restrict__ Q,
                                              const u16* __restrict__ K,
                                              const u16* __restrict__ V,
                                              u16* __restrict__ out) {
  constexpr int LDV = 132;  // padded fp32 row stride: 528B, 16B-aligned
  __shared__ __align__(16) float Qs[32 * LDV];
  __shared__ __align__(16) float Ks[32 * LDV];
  __shared__ __align__(16) float Vs[32 * LDV];
  __shared__ float Ss[32 * 33];

  const int t  = threadIdx.x;
  const int qt = blockIdx.x, bh = blockIdx.y;
  const size_t base = (size_t)bh * SEQ * DK;

  {  // load Q tile (32 x 128), bf16 -> fp32
    const u16* Qp = Q + base + (size_t)(qt * 32) * DK;
#pragma unroll
    for (int it = 0; it < 4; ++it) {
      int g = t + it * 256;
      int row = g >> 5, c4 = (g & 31) * 4;
      uint2 u = *(const uint2*)(Qp + row * DK + c4);
      float* dst = &Qs[row * LDV + c4];
      dst[0] = b2f((u16)(u.x & 0xffffu)); dst[1] = b2f((u16)(u.x >> 16));
      dst[2] = b2f((u16)(u.y & 0xffffu)); dst[3] = b2f((u16)(u.y >> 16));
    }
  }

  const int q     = t >> 3;        // query row 0..31
  const int lane8 = t & 7;
  const int d0    = lane8 * 16;    // this thread's 16 output dims
  const int qglob = qt * 32 + q;

  float o[16];
#pragma unroll
  for (int i = 0; i < 16; ++i) o[i] = 0.f;
  float m_run = -1e30f, l_run = 0.f;
  const float scale = 0.08838834764831845f;  // 1/sqrt(128)

  const int kend = (qt + 1) * 32;  // causal: skip tiles fully above diagonal
  for (int k0 = 0; k0 < kend; k0 += 32) {
    __syncthreads();  // previous iter's Ss/Vs reads done before overwrite
    const u16* Kp = K + base + (size_t)k0 * DK;
    const u16* Vp = V + base + (size_t)k0 * DK;
#pragma unroll
    for (int it = 0; it < 4; ++it) {
      int g = t + it * 256;
      int row = g >> 5, c4 = (g & 31) * 4;
      uint2 u = *(const uint2*)(Kp + row * DK + c4);
      float* dk = &Ks[row * LDV + c4];
      dk[0] = b2f((u16)(u.x & 0xffffu)); dk[1] = b2f((u16)(u.x >> 16));
      dk[2] = b2f((u16)(u.y & 0xffffu)); dk[3] = b2f((u16)(u.y >> 16));
      uint2 w = *(const uint2*)(Vp + row * DK + c4);
      float* dv = &Vs[row * LDV + c4];
      dv[0] = b2f((u16)(w.x & 0xffffu)); dv[1] = b2f((u16)(w.x >> 16));
      dv[2] = b2f((u16)(w.y & 0xffffu)); dv[3] = b2f((u16)(w.y >> 16));
    }
    __syncthreads();

    // scores: this thread does keys lane8 + {0,8,16,24} for its q
    float a0 = 0.f, a1 = 0.f, a2 = 0.f, a3 = 0.f;
    const float* qrow = &Qs[q * LDV];
    const float* k0r = &Ks[(lane8 + 0)  * LDV];
    const float* k1r = &Ks[(lane8 + 8)  * LDV];
    const float* k2r = &Ks[(lane8 + 16) * LDV];
    const float* k3r = &Ks[(lane8 + 24) * LDV];
#pragma unroll 8
    for (int d = 0; d < DK; d += 4) {
      f32x4 qv  = *(const f32x4*)(qrow + d);
      f32x4 kv0 = *(const f32x4*)(k0r + d);
      f32x4 kv1 = *(const f32x4*)(k1r + d);
      f32x4 kv2 = *(const f32x4*)(k2r + d);
      f32x4 kv3 = *(const f32x4*)(k3r + d);
      a0 += qv.x * kv0.x + qv.y * kv0.y + qv.z * kv0.z + qv.w * kv0.w;
      a1 += qv.x * kv1.x + qv.y * kv1.y + qv.z * kv1.z + qv.w * kv1.w;
      a2 += qv.x * kv2.x + qv.y * kv2.y + qv.z * kv2.z + qv.w * kv2.w;
      a3 += qv.x * kv3.x + qv.y * kv3.y + qv.z * kv3.z + qv.w * kv3.w;
    }
    int kg = k0 + lane8;
    Ss[q * 33 + lane8 + 0 ] = (kg      <= qglob) ? a0 * scale : -1e30f;
    Ss[q * 33 + lane8 + 8 ] = (kg + 8  <= qglob) ? a1 * scale : -1e30f;
    Ss[q * 33 + lane8 + 16] = (kg + 16 <= qglob) ? a2 * scale : -1e30f;
    Ss[q * 33 + lane8 + 24] = (kg + 24 <= qglob) ? a3 * scale : -1e30f;
    __syncthreads();

    // online softmax + PV (redundant across the 8 threads of a row: broadcast reads)
    const float* srow = &Ss[q * 33];
    float mx = m_run;
#pragma unroll
    for (int j = 0; j < 32; ++j) mx = fmaxf(mx, srow[j]);
    float alpha = __expf(m_run - mx);   // first tile: exp(-1e30 - finite) = 0, no NaN
#pragma unroll
    for (int i = 0; i < 16; ++i) o[i] *= alpha;
    float lsum = 0.f;
#pragma unroll 4
    for (int j = 0; j < 32; ++j) {
      float p = __expf(srow[j] - mx);   // masked: exp(-1e30 - mx) = 0
      lsum += p;
      const float* vr = &Vs[j * LDV + d0];
      f32x4 v0 = *(const f32x4*)(vr + 0);
      f32x4 v1 = *(const f32x4*)(vr + 4);
      f32x4 v2 = *(const f32x4*)(vr + 8);
      f32x4 v3 = *(const f32x4*)(vr + 12);
      o[0]  += p * v0.x; o[1]  += p * v0.y; o[2]  += p * v0.z; o[3]  += p * v0.w;
      o[4]  += p * v1.x; o[5]  += p * v1.y; o[6]  += p * v1.z; o[7]  += p * v1.w;
      o[8]  += p * v2.x; o[9]  += p * v2.y; o[10] += p * v2.z; o[11] += p * v2.w;
      o[12] += p * v3.x; o[13] += p * v3.y; o[14] += p * v3.z; o[15] += p * v3.w;
    }
    l_run = l_run * alpha + lsum;
    m_run = mx;
  }

  float inv = 1.f / l_run;
  __align__(16) u16 tmp[16];
#pragma unroll
  for (int i = 0; i < 16; ++i) tmp[i] = f2b(o[i] * inv);
  const int b = bh >> 4, h = bh & 15;
  size_t ob = ((size_t)(b * SEQ + qglob)) * D_MODEL + h * DK + d0;
  *(uint4*)&out[ob]     = *(const uint4*)&tmp[0];
  *(uint4*)&out[ob + 8] = *(const uint4*)&tmp[8];
}

// ---------------- host-side orchestration ----------------
extern "C" void kernel_launch(void* const* d_in, const int* in_sizes, int n_in,
                              void* d_out, int out_size, void* d_ws, size_t ws_size,
                              hipStream_t stream) {
  const float* x  = (const float*)d_in[0];
  const float* wq = (const float*)d_in[1];
  const float* wk = (const float*)d_in[2];
  const float* wv = (const float*)d_in[3];
  const float* wo = (const float*)d_in[4];
  const float* bo = (const float*)d_in[5];
  float* out = (float*)d_out;

  char* wsb = (char*)d_ws;
  // ws layout (bytes): total 100,663,296
  u16* xb    = (u16*)(wsb + 0);          // 16.78 MB  (reused as attn output later)
  u16* wqb   = (u16*)(wsb + 16777216);   //  8.39 MB
  u16* wkb   = (u16*)(wsb + 25165824);
  u16* wvb   = (u16*)(wsb + 33554432);
  u16* wob   = (u16*)(wsb + 41943040);
  u16* Qb    = (u16*)(wsb + 50331648);   // 16.78 MB (B,H,S,DK)
  u16* Kb    = (u16*)(wsb + 67108864);
  u16* Vb    = (u16*)(wsb + 83886080);
  u16* attnb = xb;                       // x's bf16 copy is dead after QKV GEMMs

  // 1) convert inputs to bf16
  cvt_k<<<8192, 256, 0, stream>>>(x,  xb,  MTOT * D_MODEL / 4);
  cvt_k<<<4096, 256, 0, stream>>>(wq, wqb, D_MODEL * D_MODEL / 4);
  cvt_k<<<4096, 256, 0, stream>>>(wk, wkb, D_MODEL * D_MODEL / 4);
  cvt_k<<<4096, 256, 0, stream>>>(wv, wvb, D_MODEL * D_MODEL / 4);
  cvt_k<<<4096, 256, 0, stream>>>(wo, wob, D_MODEL * D_MODEL / 4);

  // 2) Q/K/V projections (write (B,H,S,DK) bf16)
  dim3 gg(D_MODEL / 128, MTOT / 128);  // (16, 32)
  gemm_bt<<<gg, 256, 0, stream>>>(xb, wqb, MTOT, D_MODEL, D_MODEL, Qb, nullptr, nullptr, 1);
  gemm_bt<<<gg, 256, 0, stream>>>(xb, wkb, MTOT, D_MODEL, D_MODEL, Kb, nullptr, nullptr, 1);
  gemm_bt<<<gg, 256, 0, stream>>>(xb, wvb, MTOT, D_MODEL, D_MODEL, Vb, nullptr, nullptr, 1);

  // 3) RoPE on Q and K
  rope_k<<<16384, 256, 0, stream>>>(Qb);
  rope_k<<<16384, 256, 0, stream>>>(Kb);

  // 4) causal flash attention -> (B,S,H*DK) bf16
  attn_k<<<dim3(SEQ / 32, BATCH * NHEADS), 256, 0, stream>>>(Qb, Kb, Vb, attnb);

  // 5) output projection + bias -> fp32 d_out
  gemm_bt<<<gg, 256, 0, stream>>>(attnb, wob, MTOT, D_MODEL, D_MODEL, nullptr, out, bo, 0);
}

// Round 2
// 585.292 us; speedup vs baseline: 3.6376x; 3.6376x over previous
//
#include <hip/hip_runtime.h>

#define D_MODEL 2048
#define NHEADS  16
#define DK      128
#define BATCH   2
#define SEQ     2048
#define MTOT    (BATCH*SEQ)   // 4096 rows

typedef unsigned short u16;
typedef unsigned int   u32;
typedef __bf16 bf16x8 __attribute__((ext_vector_type(8)));
typedef float  f32x4  __attribute__((ext_vector_type(4)));

__device__ __forceinline__ float b2f(u16 u) {
  return __uint_as_float(((u32)u) << 16);
}
__device__ __forceinline__ u16 f2b(float f) {  // RNE fp32 -> bf16
  u32 x = __float_as_uint(f);
  x += 0x7fffu + ((x >> 16) & 1u);
  return (u16)(x >> 16);
}

// ---------------- fp32 -> bf16 bulk convert ----------------
__global__ __launch_bounds__(256) void cvt_k(const float* __restrict__ in,
                                             u16* __restrict__ out, int n4) {
  int i = blockIdx.x * 256 + threadIdx.x;
  if (i >= n4) return;
  float4 v = ((const float4*)in)[i];
  u32 lo = (u32)f2b(v.x) | ((u32)f2b(v.y) << 16);
  u32 hi = (u32)f2b(v.z) | ((u32)f2b(v.w) << 16);
  ((uint2*)out)[i] = make_uint2(lo, hi);
}

// ---------------- RoPE (in-place on bf16 (B,H,S,DK)) ----------------
__global__ __launch_bounds__(256) void rope_k(u16* __restrict__ T) {
  int idx = blockIdx.x * 256 + threadIdx.x;   // one thread per (bh,s,pair)
  int p = idx & 63;                 // pair index 0..63
  int s = (idx >> 6) & (SEQ - 1);   // position
  float freq = exp2f(-0.20762050593045951f * (float)p);
  float ang = (float)s * freq;
  float sn, cs;
  sincosf(ang, &sn, &cs);
  u32 v = *(u32*)(T + (size_t)idx * 2);
  float te = b2f((u16)(v & 0xffffu));
  float to = b2f((u16)(v >> 16));
  float e  = te * cs - to * sn;
  float od = te * sn + to * cs;
  u32 r = (u32)f2b(e) | ((u32)f2b(od) << 16);
  *(u32*)(T + (size_t)idx * 2) = r;
}

// ---------------- GEMM: Y(M,N) = A(M,K) @ B(N,K)^T, bf16 MFMA ----------------
__global__ __launch_bounds__(256) void gemm_bt(const u16* __restrict__ A,
                                               const u16* __restrict__ B,
                                               const int M, const int N, const int K,
                                               u16* __restrict__ outb,
                                               float* __restrict__ outf,
                                               const float* __restrict__ bias,
                                               const int mode) {
  constexpr int LDT = 40;
  __shared__ __align__(16) u16 As[128 * LDT];
  __shared__ __align__(16) u16 Bs[128 * LDT];

  const int t    = threadIdx.x;
  const int lane = t & 63;
  const int wave = t >> 6;
  const int wm   = wave >> 1, wn = wave & 1;
  const int quad = lane >> 4, l16 = lane & 15;
  const int m0 = blockIdx.y * 128, n0 = blockIdx.x * 128;
  const int cg = t & 3, r = t >> 2;

  f32x4 acc[4][4] = {};

  const u16* Ap = A + (size_t)(m0 + r) * K + cg * 8;
  const u16* Bp = B + (size_t)(n0 + r) * K + cg * 8;
  const size_t rowJump = (size_t)64 * K;

  for (int k0 = 0; k0 < K; k0 += 32) {
    uint4 av0 = *(const uint4*)(Ap + k0);
    uint4 av1 = *(const uint4*)(Ap + k0 + rowJump);
    uint4 bv0 = *(const uint4*)(Bp + k0);
    uint4 bv1 = *(const uint4*)(Bp + k0 + rowJump);
    __syncthreads();
    *(uint4*)&As[(r)      * LDT + cg * 8] = av0;
    *(uint4*)&As[(r + 64) * LDT + cg * 8] = av1;
    *(uint4*)&Bs[(r)      * LDT + cg * 8] = bv0;
    *(uint4*)&Bs[(r + 64) * LDT + cg * 8] = bv1;
    __syncthreads();

    bf16x8 af[4], bfr[4];
#pragma unroll
    for (int i = 0; i < 4; ++i)
      af[i] = *(const bf16x8*)&As[(wm * 64 + i * 16 + l16) * LDT + quad * 8];
#pragma unroll
    for (int j = 0; j < 4; ++j)
      bfr[j] = *(const bf16x8*)&Bs[(wn * 64 + j * 16 + l16) * LDT + quad * 8];
#pragma unroll
    for (int i = 0; i < 4; ++i)
#pragma unroll
      for (int j = 0; j < 4; ++j)
        acc[i][j] = __builtin_amdgcn_mfma_f32_16x16x32_bf16(af[i], bfr[j], acc[i][j], 0, 0, 0);
  }

#pragma unroll
  for (int i = 0; i < 4; ++i) {
#pragma unroll
    for (int j = 0; j < 4; ++j) {
#pragma unroll
      for (int rr = 0; rr < 4; ++rr) {
        int row = m0 + wm * 64 + i * 16 + quad * 4 + rr;
        int col = n0 + wn * 64 + j * 16 + l16;
        float v = acc[i][j][rr];
        if (mode == 0) {
          outf[(size_t)row * N + col] = v + bias[col];
        } else {
          int b = row >> 11;
          int s = row & (SEQ - 1);
          int h = col >> 7;
          int d = col & (DK - 1);
          outb[(((size_t)(b * NHEADS + h)) * SEQ + s) * DK + d] = f2b(v);
        }
      }
    }
  }
}

// ---------------- V transpose: (B,H,S,DK) -> (B,H,DK,S), bf16 ----------------
__global__ __launch_bounds__(256) void vt_k(const u16* __restrict__ V,
                                            u16* __restrict__ Vt) {
  constexpr int LDT = 72;
  __shared__ __align__(16) u16 tile[64 * LDT];
  const int s0 = blockIdx.x * 64, d0 = blockIdx.y * 64, bh = blockIdx.z;
  const u16* in = V + (size_t)bh * SEQ * DK;
  u16* out = Vt + (size_t)bh * DK * SEQ;
  const int t = threadIdx.x;
  const int r = t >> 3, cg = t & 7;
#pragma unroll
  for (int half = 0; half < 2; ++half) {
    uint4 v = *(const uint4*)(in + (size_t)(s0 + r + half * 32) * DK + d0 + cg * 8);
    *(uint4*)&tile[(r + half * 32) * LDT + cg * 8] = v;
  }
  __syncthreads();
#pragma unroll
  for (int half = 0; half < 2; ++half) {
    int d = (t >> 3) + half * 32;
    __align__(16) u16 tmp[8];
#pragma unroll
    for (int i = 0; i < 8; ++i) tmp[i] = tile[(cg * 8 + i) * LDT + d];
    *(uint4*)(out + (size_t)(d0 + d) * SEQ + s0 + cg * 8) = *(const uint4*)tmp;
  }
}

// ---------------- MFMA flash attention, causal ----------------
// Q,K: bf16 (B,H,S,DK) roped. Vt: bf16 (B,H,DK,S). out: bf16 (B,S,D_MODEL).
#define LDKS 136   // K tile row stride (shorts): 272B, 16B-aligned
#define LDVS 72    // Vt tile row stride: 144B
#define LDPS 72    // P tile row stride
__global__ __launch_bounds__(256) void attn_k(const u16* __restrict__ Q,
                                              const u16* __restrict__ K,
                                              const u16* __restrict__ Vt,
                                              u16* __restrict__ out) {
  __shared__ __align__(16) u16 Ks[64 * LDKS];   // 17408 B (reused for O epilogue)
  __shared__ __align__(16) u16 Vs[DK * LDVS];   // 18432 B
  __shared__ __align__(16) u16 Ps[64 * LDPS];   //  9216 B (16 rows per wave)

  const int t    = threadIdx.x;
  const int lane = t & 63;
  const int wave = t >> 6;
  const int quad = lane >> 4, l16 = lane & 15;
  const int qt   = (int)gridDim.x - 1 - (int)blockIdx.x;  // heavy blocks first
  const int bh   = blockIdx.y;
  const size_t baseQK = (size_t)bh * SEQ * DK;
  const size_t baseV  = (size_t)bh * DK * SEQ;
  const int qw = qt * 64 + wave * 16;            // wave's first query row
  const float scale = 0.08838834764831845f;      // 1/sqrt(128)

  // preload Q a-frags (held in regs for whole kernel)
  bf16x8 qf[4];
  {
    const u16* Qp = Q + baseQK + (size_t)(qw + l16) * DK + quad * 8;
#pragma unroll
    for (int kc = 0; kc < 4; ++kc) qf[kc] = *(const bf16x8*)(Qp + kc * 32);
  }

  f32x4 oacc[8] = {};
  float m_run[4] = {-1e30f, -1e30f, -1e30f, -1e30f};
  float l_run[4] = {0.f, 0.f, 0.f, 0.f};

  const int r16 = t >> 4, cg16 = t & 15;  // K staging coords
  const int rv  = t >> 3, cgv  = t & 7;   // Vt staging coords

  const int kend = (qt + 1) * 64;
  for (int k0 = 0; k0 < kend; k0 += 64) {
    __syncthreads();
    {  // stage K tile: 64 keys x 128 dims
      const u16* Kp = K + baseQK + (size_t)(k0 + r16) * DK + cg16 * 8;
#pragma unroll
      for (int it = 0; it < 4; ++it) {
        uint4 v = *(const uint4*)(Kp + (size_t)it * 16 * DK);
        *(uint4*)&Ks[(r16 + it * 16) * LDKS + cg16 * 8] = v;
      }
    }
    {  // stage Vt tile: 128 dims x 64 keys
      const u16* Vp = Vt + baseV + (size_t)rv * SEQ + k0 + cgv * 8;
#pragma unroll
      for (int it = 0; it < 4; ++it) {
        uint4 v = *(const uint4*)(Vp + (size_t)it * 32 * SEQ);
        *(uint4*)&Vs[(rv + it * 32) * LDVS + cgv * 8] = v;
      }
    }
    __syncthreads();

    if (k0 < qw + 16) {  // wave has at least one unmasked key in this tile
      // ---- QK^T: S tile 16(q) x 64(k) ----
      f32x4 sacc[4] = {};
#pragma unroll
      for (int kc = 0; kc < 4; ++kc) {
#pragma unroll
        for (int nt = 0; nt < 4; ++nt) {
          bf16x8 kf = *(const bf16x8*)&Ks[(nt * 16 + l16) * LDKS + kc * 32 + quad * 8];
          sacc[nt] = __builtin_amdgcn_mfma_f32_16x16x32_bf16(qf[kc], kf, sacc[nt], 0, 0, 0);
        }
      }

      // ---- scale + causal mask ----
      const bool needMask = (k0 + 63) > qw;  // wave-uniform
      float sv[4][4];
#pragma unroll
      for (int nt = 0; nt < 4; ++nt) {
#pragma unroll
        for (int r = 0; r < 4; ++r) {
          float v = sacc[nt][r] * scale;
          if (needMask) {
            int key  = k0 + nt * 16 + l16;
            int qrow = qw + quad * 4 + r;
            v = (key <= qrow) ? v : -1e30f;
          }
          sv[nt][r] = v;
        }
      }

      // ---- row max (across nt, then butterfly over the 16 lanes of a quad) ----
      float mx[4];
#pragma unroll
      for (int r = 0; r < 4; ++r) {
        float m = fmaxf(fmaxf(sv[0][r], sv[1][r]), fmaxf(sv[2][r], sv[3][r]));
#pragma unroll
        for (int msk = 1; msk < 16; msk <<= 1) m = fmaxf(m, __shfl_xor(m, msk));
        mx[r] = fmaxf(m, m_run[r]);
      }

      // ---- p = exp(s - mx), row sums, write P to per-wave LDS ----
      float ls[4] = {0.f, 0.f, 0.f, 0.f};
      u16* pw = &Ps[wave * 16 * LDPS];
#pragma unroll
      for (int nt = 0; nt < 4; ++nt) {
#pragma unroll
        for (int r = 0; r < 4; ++r) {
          float p = __expf(sv[nt][r] - mx[r]);
          ls[r] += p;
          pw[(quad * 4 + r) * LDPS + nt * 16 + l16] = f2b(p);
        }
      }
#pragma unroll
      for (int r = 0; r < 4; ++r) {
#pragma unroll
        for (int msk = 1; msk < 16; msk <<= 1) ls[r] += __shfl_xor(ls[r], msk);
        float alpha = __expf(m_run[r] - mx[r]);
        l_run[r] = l_run[r] * alpha + ls[r];
        m_run[r] = mx[r];
#pragma unroll
        for (int nt = 0; nt < 8; ++nt) oacc[nt][r] *= alpha;
      }

      // ---- P (C-layout) -> A-frags via per-wave LDS (no barrier needed) ----
      bf16x8 pf[2];
      const u16* pr = &pw[l16 * LDPS + quad * 8];
      pf[0] = *(const bf16x8*)(pr);
      pf[1] = *(const bf16x8*)(pr + 32);

      // ---- PV: O tile 16(q) x 128(d) ----
#pragma unroll
      for (int kc = 0; kc < 2; ++kc) {
#pragma unroll
        for (int nt = 0; nt < 8; ++nt) {
          bf16x8 vf = *(const bf16x8*)&Vs[(nt * 16 + l16) * LDVS + kc * 32 + quad * 8];
          oacc[nt] = __builtin_amdgcn_mfma_f32_16x16x32_bf16(pf[kc], vf, oacc[nt], 0, 0, 0);
        }
      }
    }
  }

  // ---- epilogue: normalize, stage to LDS (reuse Ks), coalesced store ----
  float inv[4];
#pragma unroll
  for (int r = 0; r < 4; ++r) inv[r] = 1.f / l_run[r];
  __syncthreads();  // all waves done with Ks reads
#pragma unroll
  for (int nt = 0; nt < 8; ++nt) {
#pragma unroll
    for (int r = 0; r < 4; ++r) {
      Ks[(wave * 16 + quad * 4 + r) * LDKS + nt * 16 + l16] = f2b(oacc[nt][r] * inv[r]);
    }
  }
  __syncthreads();
  const int b = bh >> 4, h = bh & 15;
#pragma unroll
  for (int it = 0; it < 4; ++it) {
    int row = (t >> 4) + it * 16;
    uint4 v = *(const uint4*)&Ks[row * LDKS + (t & 15) * 8];
    *(uint4*)(out + ((size_t)(b * SEQ + qt * 64 + row)) * D_MODEL + h * DK + (t & 15) * 8) = v;
  }
}

// ---------------- host-side orchestration ----------------
extern "C" void kernel_launch(void* const* d_in, const int* in_sizes, int n_in,
                              void* d_out, int out_size, void* d_ws, size_t ws_size,
                              hipStream_t stream) {
  const float* x  = (const float*)d_in[0];
  const float* wq = (const float*)d_in[1];
  const float* wk = (const float*)d_in[2];
  const float* wv = (const float*)d_in[3];
  const float* wo = (const float*)d_in[4];
  const float* bo = (const float*)d_in[5];
  float* out = (float*)d_out;

  char* wsb = (char*)d_ws;
  // ws layout (bytes): total 100,663,296
  u16* xb    = (u16*)(wsb + 0);          // 16.78 MB  (reused as attn output later)
  u16* wqb   = (u16*)(wsb + 16777216);   //  8.39 MB  (reused as Vt low half)
  u16* wkb   = (u16*)(wsb + 25165824);   //  8.39 MB  (reused as Vt high half)
  u16* wvb   = (u16*)(wsb + 33554432);
  u16* wob   = (u16*)(wsb + 41943040);
  u16* Qb    = (u16*)(wsb + 50331648);   // 16.78 MB (B,H,S,DK)
  u16* Kb    = (u16*)(wsb + 67108864);
  u16* Vb    = (u16*)(wsb + 83886080);
  u16* attnb = xb;                       // x's bf16 copy dead after QKV GEMMs
  u16* Vtb   = wqb;                      // wq/wk bf16 dead after Q/K GEMMs (16.78 MB span)

  // 1) convert inputs to bf16
  cvt_k<<<8192, 256, 0, stream>>>(x,  xb,  MTOT * D_MODEL / 4);
  cvt_k<<<4096, 256, 0, stream>>>(wq, wqb, D_MODEL * D_MODEL / 4);
  cvt_k<<<4096, 256, 0, stream>>>(wk, wkb, D_MODEL * D_MODEL / 4);
  cvt_k<<<4096, 256, 0, stream>>>(wv, wvb, D_MODEL * D_MODEL / 4);
  cvt_k<<<4096, 256, 0, stream>>>(wo, wob, D_MODEL * D_MODEL / 4);

  // 2) Q/K/V projections (write (B,H,S,DK) bf16)
  dim3 gg(D_MODEL / 128, MTOT / 128);  // (16, 32)
  gemm_bt<<<gg, 256, 0, stream>>>(xb, wqb, MTOT, D_MODEL, D_MODEL, Qb, nullptr, nullptr, 1);
  gemm_bt<<<gg, 256, 0, stream>>>(xb, wkb, MTOT, D_MODEL, D_MODEL, Kb, nullptr, nullptr, 1);

  // 3) RoPE on Q and K
  rope_k<<<16384, 256, 0, stream>>>(Qb);
  rope_k<<<16384, 256, 0, stream>>>(Kb);

  // V projection, then transpose into (B,H,DK,S) over the dead wq/wk buffers
  gemm_bt<<<gg, 256, 0, stream>>>(xb, wvb, MTOT, D_MODEL, D_MODEL, Vb, nullptr, nullptr, 1);
  vt_k<<<dim3(SEQ / 64, DK / 64, BATCH * NHEADS), 256, 0, stream>>>(Vb, Vtb);

  // 4) causal MFMA flash attention -> (B,S,D_MODEL) bf16
  attn_k<<<dim3(SEQ / 64, BATCH * NHEADS), 256, 0, stream>>>(Qb, Kb, Vtb, attnb);

  // 5) output projection + bias -> fp32 d_out
  gemm_bt<<<gg, 256, 0, stream>>>(attnb, wob, MTOT, D_MODEL, D_MODEL, nullptr, out, bo, 0);
}